// Round 10
// baseline (48.007 us; speedup 1.0000x reference)
//
#include <hip/hip_runtime.h>

#define BB 4
#define CC 512    // C_CTX
#define TDIM 512  // T
#define HH 128
#define TT 4      // t-rows per block
#define CHK 128   // c-rows per chunk
#define NCHK 4    // chunks

// ---------------- prep: key/query/value projections (f32 to ws) -------------
__global__ __launch_bounds__(128) void prep_kernel(
    const float* __restrict__ ctx_x, const float* __restrict__ ctx_y,
    const float* __restrict__ tgt_x,
    const float* __restrict__ W_in, const float* __restrict__ b_in,
    const float* __restrict__ W_ctx, const float* __restrict__ b_ctx,
    float* __restrict__ key, float* __restrict__ query, float* __restrict__ value)
{
    int row = blockIdx.x;     // b*512 + r
    int h   = threadIdx.x;    // 0..127

    float4 cx = ((const float4*)ctx_x)[row];
    float2 cy = ((const float2*)ctx_y)[row];
    float4 tx = ((const float4*)tgt_x)[row];

    float wi0 = W_in[0*HH+h], wi1 = W_in[1*HH+h], wi2 = W_in[2*HH+h];
    float wi3 = W_in[3*HH+h], wi4 = W_in[4*HH+h];
    float wc0 = W_ctx[0*HH+h], wc1 = W_ctx[1*HH+h], wc2 = W_ctx[2*HH+h];
    float bi  = b_in[h], bc = b_ctx[h];

    value[row*HH+h] = fmaf(cx.x,wi0, fmaf(cx.y,wi1, fmaf(cx.z,wi2, fmaf(cy.x,wi3, fmaf(cy.y,wi4, bi)))));
    key  [row*HH+h] = fmaf(cx.x,wc0, fmaf(cx.y,wc1, fmaf(cx.z,wc2, bc)));
    query[row*HH+h] = fmaf(tx.x,wc0, fmaf(tx.y,wc1, fmaf(tx.z,wc2, bc)));
}

// ---------- fused flash, 512 threads (8 waves), pipelined SCORE(ch+1)∥PV(ch).
// grid = 512 blocks -> 2 blocks/CU -> 16 waves/CU = 4 waves/SIMD.
// Register-lean mapping (float2 h-slices) to stay <=128 VGPR.
__global__ __launch_bounds__(512, 4) void fused_kernel(
    const float* __restrict__ key, const float* __restrict__ query,
    const float* __restrict__ value, const float* __restrict__ W_tgt,
    const float* __restrict__ b_tgt, float* __restrict__ out)
{
    const int bx   = blockIdx.x;          // b*128 + t-quad
    const int b    = bx >> 7;
    const int t0   = (bx & 127) * TT;
    const int tid  = threadIdx.x;         // 0..511
    const int wave = tid >> 6;            // 0..7
    const int lane = tid & 63;

    __shared__ __align__(16) float s[2][TT][CHK];      // 4 KB raw scores (dbuf)
    __shared__ __align__(16) float pT[2][CHK][TT];     // 4 KB exp, transposed (dbuf)
    __shared__ __align__(16) float fct[2][TT];         // rescale factors
    __shared__ __align__(16) float linv[TT];
    __shared__ __align__(16) float partial[8][TT][HH]; // 16 KB PV partials (end)
    __shared__ __align__(16) float rep[TT][HH];        // 2 KB

    // --- score role: (cq = c-quad 0..31, hq = h-slice 0..15, 2 floats each).
    //     q held in 32 registers (float2 x 4t x 4j).
    const int cq = tid >> 4;   // 0..31
    const int hq = tid & 15;   // 0..15
    float2 qr[TT][4];
    #pragma unroll
    for (int t = 0; t < TT; ++t)
        #pragma unroll
        for (int j = 0; j < 4; ++j)
            qr[t][j] = *(const float2*)&query[(b*TDIM + t0 + t)*HH + j*32 + hq*2];

    // --- PV role: wave owns 16 c-rows; lane = h-pair (h = lane*2) ---
    float2 acc[TT];
    #pragma unroll
    for (int t = 0; t < TT; ++t) acc[t] = make_float2(0.f, 0.f);
    float m_run = -1e30f, l_run = 0.f;   // valid in waves 0..3 (t = wave)

    auto SCORE = [&](int ch, int p) {
        const float* kp = &key[(b*CC + ch*CHK + cq*4)*HH];
        float a0[TT], a1[TT], a2[TT], a3[TT];
        #pragma unroll
        for (int t = 0; t < TT; ++t) { a0[t]=0.f; a1[t]=0.f; a2[t]=0.f; a3[t]=0.f; }
        #pragma unroll
        for (int j = 0; j < 4; ++j) {
            const int hb = j*32 + hq*2;
            float2 k0 = *(const float2*)(kp + 0*HH + hb);
            float2 k1 = *(const float2*)(kp + 1*HH + hb);
            float2 k2 = *(const float2*)(kp + 2*HH + hb);
            float2 k3 = *(const float2*)(kp + 3*HH + hb);
            #pragma unroll
            for (int t = 0; t < TT; ++t) {
                float2 qv = qr[t][j];
                a0[t] += fabsf(k0.x-qv.x) + fabsf(k0.y-qv.y);
                a1[t] += fabsf(k1.x-qv.x) + fabsf(k1.y-qv.y);
                a2[t] += fabsf(k2.x-qv.x) + fabsf(k2.y-qv.y);
                a3[t] += fabsf(k3.x-qv.x) + fabsf(k3.y-qv.y);
            }
        }
        #pragma unroll
        for (int t = 0; t < TT; ++t) {
            float v0=a0[t], v1=a1[t], v2=a2[t], v3=a3[t];
            v0 += __shfl_xor(v0,1); v0 += __shfl_xor(v0,2); v0 += __shfl_xor(v0,4); v0 += __shfl_xor(v0,8);
            v1 += __shfl_xor(v1,1); v1 += __shfl_xor(v1,2); v1 += __shfl_xor(v1,4); v1 += __shfl_xor(v1,8);
            v2 += __shfl_xor(v2,1); v2 += __shfl_xor(v2,2); v2 += __shfl_xor(v2,4); v2 += __shfl_xor(v2,8);
            v3 += __shfl_xor(v3,1); v3 += __shfl_xor(v3,2); v3 += __shfl_xor(v3,4); v3 += __shfl_xor(v3,8);
            if (hq == 0)
                *(float4*)&s[p][t][cq*4] =
                    make_float4(-0.5f*v0, -0.5f*v1, -0.5f*v2, -0.5f*v3);
        }
    };

    auto SOFTMAX = [&](int p) {           // waves 0..3 only; wave owns t = wave
        float x0 = s[p][wave][lane], x1 = s[p][wave][lane+64];
        float mc = fmaxf(x0, x1);
        #pragma unroll
        for (int msk = 32; msk; msk >>= 1) mc = fmaxf(mc, __shfl_xor(mc, msk));
        float m_new = fmaxf(m_run, mc);
        float e0 = __expf(x0 - m_new), e1 = __expf(x1 - m_new);
        float sum = e0 + e1;
        #pragma unroll
        for (int msk = 32; msk; msk >>= 1) sum += __shfl_xor(sum, msk);
        float f = __expf(m_run - m_new);
        l_run = fmaf(l_run, f, sum);
        m_run = m_new;
        pT[p][lane   ][wave] = e0;
        pT[p][lane+64][wave] = e1;
        if (lane == 0) fct[p][wave] = f;
    };

    auto PV = [&](int ch, int p) {
        const float4 fv = *(const float4*)&fct[p][0];
        acc[0].x *= fv.x; acc[0].y *= fv.x;
        acc[1].x *= fv.y; acc[1].y *= fv.y;
        acc[2].x *= fv.z; acc[2].y *= fv.z;
        acc[3].x *= fv.w; acc[3].y *= fv.w;
        const int cbase = wave * 16;
        const float* vp = &value[(b*CC + ch*CHK + cbase)*HH + lane*2];
        #pragma unroll 4
        for (int c = 0; c < 16; ++c) {
            float4 p4 = *(const float4*)&pT[p][cbase + c][0];  // broadcast
            float2 vv = *(const float2*)(vp + c*HH);           // coalesced
            acc[0].x = fmaf(p4.x, vv.x, acc[0].x); acc[0].y = fmaf(p4.x, vv.y, acc[0].y);
            acc[1].x = fmaf(p4.y, vv.x, acc[1].x); acc[1].y = fmaf(p4.y, vv.y, acc[1].y);
            acc[2].x = fmaf(p4.z, vv.x, acc[2].x); acc[2].y = fmaf(p4.z, vv.y, acc[2].y);
            acc[3].x = fmaf(p4.w, vv.x, acc[3].x); acc[3].y = fmaf(p4.w, vv.y, acc[3].y);
        }
    };

    // ---- pipelined schedule: score(ch+1) ∥ PV(ch) in one region ----
    SCORE(0, 0);
    __syncthreads();
    if (wave < 4) SOFTMAX(0);
    __syncthreads();
    SCORE(1, 1);  PV(0, 0);
    __syncthreads();
    if (wave < 4) SOFTMAX(1);
    __syncthreads();
    SCORE(2, 0);  PV(1, 1);
    __syncthreads();
    if (wave < 4) SOFTMAX(0);
    __syncthreads();
    SCORE(3, 1);  PV(2, 0);
    __syncthreads();
    if (wave < 4) SOFTMAX(1);
    __syncthreads();
    PV(3, 1);

    // ---- final: partials -> reduce -> normalize -> projection ----
    if (wave < 4 && lane == 0) linv[wave] = 1.f / l_run;
    #pragma unroll
    for (int t = 0; t < TT; ++t)
        *(float2*)&partial[wave][t][lane*2] = acc[t];
    __syncthreads();

    {   // 512 threads, 512 rep elements: one element each
        const int t = tid >> 7, h = tid & 127;
        float r = 0.f;
        #pragma unroll
        for (int gg = 0; gg < 8; ++gg) r += partial[gg][t][h];
        rep[t][h] = r * linv[t];
    }
    __syncthreads();

    {   // projection: thread (lt 0..3, h) -> one output row each
        const int lt = tid >> 7, h = tid & 127;
        float o = b_tgt[h];
        for (int k = 0; k < HH; k += 4) {
            float4 r0 = *(const float4*)&rep[lt][k];
            float w0 = W_tgt[(k+0)*HH + h];
            float w1 = W_tgt[(k+1)*HH + h];
            float w2 = W_tgt[(k+2)*HH + h];
            float w3 = W_tgt[(k+3)*HH + h];
            o = fmaf(r0.x,w0, fmaf(r0.y,w1, fmaf(r0.z,w2, fmaf(r0.w,w3, o))));
        }
        out[(b*TDIM + t0 + lt)*HH + h] = o;
    }
}

extern "C" void kernel_launch(void* const* d_in, const int* in_sizes, int n_in,
                              void* d_out, int out_size, void* d_ws, size_t ws_size,
                              hipStream_t stream) {
    const float* ctx_x = (const float*)d_in[0];
    const float* ctx_y = (const float*)d_in[1];
    const float* tgt_x = (const float*)d_in[2];
    const float* W_in  = (const float*)d_in[3];
    const float* b_in  = (const float*)d_in[4];
    const float* W_ctx = (const float*)d_in[5];
    const float* b_ctx = (const float*)d_in[6];
    const float* W_tgt = (const float*)d_in[7];
    const float* b_tgt = (const float*)d_in[8];

    float* ws    = (float*)d_ws;
    float* key   = ws;                      // 262144 f32
    float* query = ws + 1*BB*CC*HH;         // 262144
    float* value = ws + 2*BB*CC*HH;         // 262144

    prep_kernel<<<BB*CC, 128, 0, stream>>>(ctx_x, ctx_y, tgt_x,
                                           W_in, b_in, W_ctx, b_ctx,
                                           key, query, value);
    fused_kernel<<<BB*(TDIM/TT), 512, 0, stream>>>(key, query, value,
                                                   W_tgt, b_tgt, (float*)d_out);
}

// Round 11
// 36.374 us; speedup vs baseline: 1.3198x; 1.3198x over previous
//
#include <hip/hip_runtime.h>

#define BB 4
#define CC 512    // C_CTX
#define TDIM 512  // T
#define HH 128
#define TT 4      // t-rows per block
#define NW 4      // waves per block
#define CPW 128   // c-rows per wave
#define SC 32     // c-rows per sub-chunk
#define NSC 4     // sub-chunks per wave

// ---------------- prep: key/query/value projections (f32 to ws) -------------
__global__ __launch_bounds__(128) void prep_kernel(
    const float* __restrict__ ctx_x, const float* __restrict__ ctx_y,
    const float* __restrict__ tgt_x,
    const float* __restrict__ W_in, const float* __restrict__ b_in,
    const float* __restrict__ W_ctx, const float* __restrict__ b_ctx,
    float* __restrict__ key, float* __restrict__ query, float* __restrict__ value)
{
    int row = blockIdx.x;     // b*512 + r
    int h   = threadIdx.x;    // 0..127

    float4 cx = ((const float4*)ctx_x)[row];
    float2 cy = ((const float2*)ctx_y)[row];
    float4 tx = ((const float4*)tgt_x)[row];

    float wi0 = W_in[0*HH+h], wi1 = W_in[1*HH+h], wi2 = W_in[2*HH+h];
    float wi3 = W_in[3*HH+h], wi4 = W_in[4*HH+h];
    float wc0 = W_ctx[0*HH+h], wc1 = W_ctx[1*HH+h], wc2 = W_ctx[2*HH+h];
    float bi  = b_in[h], bc = b_ctx[h];

    value[row*HH+h] = fmaf(cx.x,wi0, fmaf(cx.y,wi1, fmaf(cx.z,wi2, fmaf(cy.x,wi3, fmaf(cy.y,wi4, bi)))));
    key  [row*HH+h] = fmaf(cx.x,wc0, fmaf(cx.y,wc1, fmaf(cx.z,wc2, bc)));
    query[row*HH+h] = fmaf(tx.x,wc0, fmaf(tx.y,wc1, fmaf(tx.z,wc2, bc)));
}

// ---------- fused flash, WAVE-INDEPENDENT: each wave owns 128 c-rows with its
// own online-softmax (m,l); SCORE->SM->PV handoff stays within the wave via
// wave-private LDS (program order, no barriers). Only 2 __syncthreads total.
// grid = BB*(TDIM/TT) = 512 blocks, 256 threads, ~15 KB LDS.
__global__ __launch_bounds__(256) void fused_kernel(
    const float* __restrict__ key, const float* __restrict__ query,
    const float* __restrict__ value, const float* __restrict__ W_tgt,
    const float* __restrict__ b_tgt, float* __restrict__ out)
{
    const int bx   = blockIdx.x;          // b*128 + t-quad
    const int b    = bx >> 7;
    const int t0   = (bx & 127) * TT;
    const int tid  = threadIdx.x;
    const int wv   = tid >> 6;            // wave 0..3: owns c [wv*128, wv*128+128)
    const int lane = tid & 63;

    __shared__ __align__(16) float s_w[NW][TT][SC];      // 2 KB wave-private scores
    __shared__ __align__(16) float pT_w[NW][SC][TT];     // 2 KB wave-private exp^T
    __shared__ __align__(16) float f_w[NW][TT];          // rescale factors
    __shared__ __align__(16) float2 ml_w[NW][TT];        // final (m,l) per wave
    __shared__ __align__(16) float partial[NW][TT][HH];  // 8 KB wave PV partials
    __shared__ __align__(16) float rep[TT][HH];          // 2 KB

    // --- score role: (cl = c-quad 0..7 within sub-chunk, hq = h-slice 0..7).
    //     q held in 64 registers (float4 x 4t x 4j).
    const int cl = lane >> 3;  // 0..7
    const int hq = lane & 7;   // 0..7
    float4 qr[TT][4];
    #pragma unroll
    for (int t = 0; t < TT; ++t)
        #pragma unroll
        for (int j = 0; j < 4; ++j)
            qr[t][j] = *(const float4*)&query[(b*TDIM + t0 + t)*HH + j*32 + hq*4];

    // --- softmax role: lane group tg = lane>>4 owns t-row tg
    const int tg = lane >> 4;
    const int ci = lane & 15;
    // --- PV role: cs = c-half of sub-chunk, hv -> h = hv*4
    const int cs = lane >> 5;
    const int hv = lane & 31;

    float4 acc[TT];
    #pragma unroll
    for (int t = 0; t < TT; ++t) acc[t] = make_float4(0.f,0.f,0.f,0.f);
    float m_run = -1e30f, l_run = 0.f;    // per-lane, for t = tg

    #pragma unroll 1
    for (int scix = 0; scix < NSC; ++scix) {
        const int cbase = wv*CPW + scix*SC;

        // ---- SCORE: 32 rows, all 4 t ----
        {
            const float* kp = &key[(b*CC + cbase + cl*4)*HH];
            float a0[TT], a1[TT], a2[TT], a3[TT];
            #pragma unroll
            for (int t = 0; t < TT; ++t) { a0[t]=0.f; a1[t]=0.f; a2[t]=0.f; a3[t]=0.f; }
            #pragma unroll
            for (int j = 0; j < 4; ++j) {
                const int hb = j*32 + hq*4;
                float4 k0 = *(const float4*)(kp + 0*HH + hb);
                float4 k1 = *(const float4*)(kp + 1*HH + hb);
                float4 k2 = *(const float4*)(kp + 2*HH + hb);
                float4 k3 = *(const float4*)(kp + 3*HH + hb);
                #pragma unroll
                for (int t = 0; t < TT; ++t) {
                    float4 qv = qr[t][j];
                    a0[t] += fabsf(k0.x-qv.x)+fabsf(k0.y-qv.y)+fabsf(k0.z-qv.z)+fabsf(k0.w-qv.w);
                    a1[t] += fabsf(k1.x-qv.x)+fabsf(k1.y-qv.y)+fabsf(k1.z-qv.z)+fabsf(k1.w-qv.w);
                    a2[t] += fabsf(k2.x-qv.x)+fabsf(k2.y-qv.y)+fabsf(k2.z-qv.z)+fabsf(k2.w-qv.w);
                    a3[t] += fabsf(k3.x-qv.x)+fabsf(k3.y-qv.y)+fabsf(k3.z-qv.z)+fabsf(k3.w-qv.w);
                }
            }
            #pragma unroll
            for (int t = 0; t < TT; ++t) {
                float v0=a0[t], v1=a1[t], v2=a2[t], v3=a3[t];
                v0 += __shfl_xor(v0,1); v0 += __shfl_xor(v0,2); v0 += __shfl_xor(v0,4);
                v1 += __shfl_xor(v1,1); v1 += __shfl_xor(v1,2); v1 += __shfl_xor(v1,4);
                v2 += __shfl_xor(v2,1); v2 += __shfl_xor(v2,2); v2 += __shfl_xor(v2,4);
                v3 += __shfl_xor(v3,1); v3 += __shfl_xor(v3,2); v3 += __shfl_xor(v3,4);
                if (hq == 0)
                    *(float4*)&s_w[wv][t][cl*4] =
                        make_float4(-0.5f*v0, -0.5f*v1, -0.5f*v2, -0.5f*v3);
            }
        }
        // same-wave LDS handoff: no barrier needed

        // ---- per-wave online softmax: t-group tg (16 lanes) owns t = tg ----
        {
            float x0 = s_w[wv][tg][ci*2], x1 = s_w[wv][tg][ci*2+1];
            float mc = fmaxf(x0, x1);
            mc = fmaxf(mc, __shfl_xor(mc,1)); mc = fmaxf(mc, __shfl_xor(mc,2));
            mc = fmaxf(mc, __shfl_xor(mc,4)); mc = fmaxf(mc, __shfl_xor(mc,8));
            float m_new = fmaxf(m_run, mc);
            float e0 = __expf(x0 - m_new), e1 = __expf(x1 - m_new);
            float sm = e0 + e1;
            sm += __shfl_xor(sm,1); sm += __shfl_xor(sm,2);
            sm += __shfl_xor(sm,4); sm += __shfl_xor(sm,8);
            float f = __expf(m_run - m_new);
            l_run = fmaf(l_run, f, sm);
            m_run = m_new;
            pT_w[wv][ci*2  ][tg] = e0;
            pT_w[wv][ci*2+1][tg] = e1;
            if (ci == 0) f_w[wv][tg] = f;
        }

        // ---- PV: rescale + accumulate this sub-chunk ----
        {
            const float4 fv = *(const float4*)&f_w[wv][0];
            acc[0].x*=fv.x; acc[0].y*=fv.x; acc[0].z*=fv.x; acc[0].w*=fv.x;
            acc[1].x*=fv.y; acc[1].y*=fv.y; acc[1].z*=fv.y; acc[1].w*=fv.y;
            acc[2].x*=fv.z; acc[2].y*=fv.z; acc[2].z*=fv.z; acc[2].w*=fv.z;
            acc[3].x*=fv.w; acc[3].y*=fv.w; acc[3].z*=fv.w; acc[3].w*=fv.w;
            const float* vp = &value[(b*CC + cbase + cs*16)*HH + hv*4];
            #pragma unroll 4
            for (int i = 0; i < 16; ++i) {
                float4 p4 = *(const float4*)&pT_w[wv][cs*16 + i][0];
                float4 vv = *(const float4*)(vp + i*HH);
                acc[0].x=fmaf(p4.x,vv.x,acc[0].x); acc[0].y=fmaf(p4.x,vv.y,acc[0].y);
                acc[0].z=fmaf(p4.x,vv.z,acc[0].z); acc[0].w=fmaf(p4.x,vv.w,acc[0].w);
                acc[1].x=fmaf(p4.y,vv.x,acc[1].x); acc[1].y=fmaf(p4.y,vv.y,acc[1].y);
                acc[1].z=fmaf(p4.y,vv.z,acc[1].z); acc[1].w=fmaf(p4.y,vv.w,acc[1].w);
                acc[2].x=fmaf(p4.z,vv.x,acc[2].x); acc[2].y=fmaf(p4.z,vv.y,acc[2].y);
                acc[2].z=fmaf(p4.z,vv.z,acc[2].z); acc[2].w=fmaf(p4.z,vv.w,acc[2].w);
                acc[3].x=fmaf(p4.w,vv.x,acc[3].x); acc[3].y=fmaf(p4.w,vv.y,acc[3].y);
                acc[3].z=fmaf(p4.w,vv.z,acc[3].z); acc[3].w=fmaf(p4.w,vv.w,acc[3].w);
            }
        }
    }

    // ---- merge cs-halves in-register, publish wave partials ----
    #pragma unroll
    for (int t = 0; t < TT; ++t) {
        acc[t].x += __shfl_xor(acc[t].x, 32);
        acc[t].y += __shfl_xor(acc[t].y, 32);
        acc[t].z += __shfl_xor(acc[t].z, 32);
        acc[t].w += __shfl_xor(acc[t].w, 32);
    }
    if (cs == 0) {
        #pragma unroll
        for (int t = 0; t < TT; ++t)
            *(float4*)&partial[wv][t][hv*4] = acc[t];
    }
    if (ci == 0) ml_w[wv][tg] = make_float2(m_run, l_run);
    __syncthreads();

    // ---- flash-merge 4 wave partials -> rep ----
    for (int e = tid; e < TT*HH; e += 256) {
        const int t = e >> 7, h = e & 127;
        float mw0 = ml_w[0][t].x, lw0 = ml_w[0][t].y;
        float mw1 = ml_w[1][t].x, lw1 = ml_w[1][t].y;
        float mw2 = ml_w[2][t].x, lw2 = ml_w[2][t].y;
        float mw3 = ml_w[3][t].x, lw3 = ml_w[3][t].y;
        float M = fmaxf(fmaxf(mw0, mw1), fmaxf(mw2, mw3));
        float a0 = __expf(mw0-M), a1 = __expf(mw1-M);
        float a2 = __expf(mw2-M), a3 = __expf(mw3-M);
        float L = fmaf(a0,lw0, fmaf(a1,lw1, fmaf(a2,lw2, a3*lw3)));
        float r = a0*partial[0][t][h] + a1*partial[1][t][h]
                + a2*partial[2][t][h] + a3*partial[3][t][h];
        rep[t][h] = r / L;
    }
    __syncthreads();

    // ---- projection: thread (lt, h) -> rows lt, lt+2 ----
    {
        const int lt = tid >> 7, h = tid & 127;
        float o0 = b_tgt[h], o1 = o0;
        for (int k = 0; k < HH; k += 4) {
            float4 r0 = *(const float4*)&rep[lt    ][k];
            float4 r1 = *(const float4*)&rep[lt + 2][k];
            float w0 = W_tgt[(k+0)*HH + h];
            float w1 = W_tgt[(k+1)*HH + h];
            float w2 = W_tgt[(k+2)*HH + h];
            float w3 = W_tgt[(k+3)*HH + h];
            o0 = fmaf(r0.x,w0, fmaf(r0.y,w1, fmaf(r0.z,w2, fmaf(r0.w,w3, o0))));
            o1 = fmaf(r1.x,w0, fmaf(r1.y,w1, fmaf(r1.z,w2, fmaf(r1.w,w3, o1))));
        }
        out[(b*TDIM + t0 + lt    )*HH + h] = o0;
        out[(b*TDIM + t0 + lt + 2)*HH + h] = o1;
    }
}

extern "C" void kernel_launch(void* const* d_in, const int* in_sizes, int n_in,
                              void* d_out, int out_size, void* d_ws, size_t ws_size,
                              hipStream_t stream) {
    const float* ctx_x = (const float*)d_in[0];
    const float* ctx_y = (const float*)d_in[1];
    const float* tgt_x = (const float*)d_in[2];
    const float* W_in  = (const float*)d_in[3];
    const float* b_in  = (const float*)d_in[4];
    const float* W_ctx = (const float*)d_in[5];
    const float* b_ctx = (const float*)d_in[6];
    const float* W_tgt = (const float*)d_in[7];
    const float* b_tgt = (const float*)d_in[8];

    float* ws    = (float*)d_ws;
    float* key   = ws;                      // 262144 f32
    float* query = ws + 1*BB*CC*HH;         // 262144
    float* value = ws + 2*BB*CC*HH;         // 262144

    prep_kernel<<<BB*CC, 128, 0, stream>>>(ctx_x, ctx_y, tgt_x,
                                           W_in, b_in, W_ctx, b_ctx,
                                           key, query, value);
    fused_kernel<<<BB*(TDIM/TT), 256, 0, stream>>>(key, query, value,
                                                   W_tgt, b_tgt, (float*)d_out);
}

// Round 12
// 32.489 us; speedup vs baseline: 1.4776x; 1.1196x over previous
//
#include <hip/hip_runtime.h>

#define BB 4
#define CC 512    // C_CTX
#define TDIM 512  // T
#define HH 128
#define TT 8      // t-rows per block
#define NR 4      // c-ranges (one per wave-pair)
#define CPW 128   // c-rows per range

// ---------------- prep: key/query/value projections (f32 to ws) -------------
__global__ __launch_bounds__(128) void prep_kernel(
    const float* __restrict__ ctx_x, const float* __restrict__ ctx_y,
    const float* __restrict__ tgt_x,
    const float* __restrict__ W_in, const float* __restrict__ b_in,
    const float* __restrict__ W_ctx, const float* __restrict__ b_ctx,
    float* __restrict__ key, float* __restrict__ query, float* __restrict__ value)
{
    int row = blockIdx.x;     // b*512 + r
    int h   = threadIdx.x;    // 0..127

    float4 cx = ((const float4*)ctx_x)[row];
    float2 cy = ((const float2*)ctx_y)[row];
    float4 tx = ((const float4*)tgt_x)[row];

    float wi0 = W_in[0*HH+h], wi1 = W_in[1*HH+h], wi2 = W_in[2*HH+h];
    float wi3 = W_in[3*HH+h], wi4 = W_in[4*HH+h];
    float wc0 = W_ctx[0*HH+h], wc1 = W_ctx[1*HH+h], wc2 = W_ctx[2*HH+h];
    float bi  = b_in[h], bc = b_ctx[h];

    value[row*HH+h] = fmaf(cx.x,wi0, fmaf(cx.y,wi1, fmaf(cx.z,wi2, fmaf(cy.x,wi3, fmaf(cy.y,wi4, bi)))));
    key  [row*HH+h] = fmaf(cx.x,wc0, fmaf(cx.y,wc1, fmaf(cx.z,wc2, bc)));
    query[row*HH+h] = fmaf(tx.x,wc0, fmaf(tx.y,wc1, fmaf(tx.z,wc2, bc)));
}

// ---------- fused, traffic-halved: TT=8 rows per block, 512 threads.
// 8 waves = 4 c-ranges x 2 t-halves; each wave fully independent:
// score(own 128 c) -> single-pass softmax -> PV (reg acc). 2 barriers total.
// grid = BB*(TDIM/TT) = 256 blocks; key+value read ONCE per block (512 KB).
__global__ __launch_bounds__(512) void fused_kernel(
    const float* __restrict__ key, const float* __restrict__ query,
    const float* __restrict__ value, const float* __restrict__ W_tgt,
    const float* __restrict__ b_tgt, float* __restrict__ out)
{
    const int bx   = blockIdx.x;          // b*64 + tb
    const int b    = bx >> 6;
    const int t0   = (bx & 63) * TT;
    const int tid  = threadIdx.x;         // 0..511
    const int wave = tid >> 6;            // 0..7
    const int cr   = wave & 3;            // c-range [cr*128, cr*128+128)
    const int th   = wave >> 2;           // t-half: rows th*4 .. th*4+3
    const int lane = tid & 63;

    __shared__ __align__(16) float sbuf[8][4][128];    // 16 KB wave-private scores
    __shared__ __align__(16) float pTbuf[8][128][4];   // 16 KB wave-private exp^T
    __shared__ __align__(16) float2 ml[8][4];          // (m, l) per wave per t-local

    float (*rep)[HH]        = (float (*)[HH])&sbuf[0][0][0];      // [8][128], aliases dead sbuf
    float (*partial)[4][HH] = (float (*)[4][HH])&pTbuf[0][0][0];  // [8][4][128], aliases own pT

    // --- score role: (cl = c-quad 0..7, hq = h-slice 0..7); q in 64 VGPR ---
    const int cl = lane >> 3;
    const int hq = lane & 7;
    float4 qr[4][4];
    #pragma unroll
    for (int tt = 0; tt < 4; ++tt)
        #pragma unroll
        for (int j = 0; j < 4; ++j)
            qr[tt][j] = *(const float4*)&query[(b*TDIM + t0 + th*4 + tt)*HH + j*32 + hq*4];

    // ---- SCORE: 4 passes x 32 rows, uninterrupted streaming ----
    #pragma unroll 1
    for (int pp = 0; pp < 4; ++pp) {
        const int crow = cr*CPW + pp*32 + cl*4;
        const float* kp = &key[(b*CC + crow)*HH];
        float a0[4], a1[4], a2[4], a3[4];
        #pragma unroll
        for (int tt = 0; tt < 4; ++tt) { a0[tt]=0.f; a1[tt]=0.f; a2[tt]=0.f; a3[tt]=0.f; }
        #pragma unroll
        for (int j = 0; j < 4; ++j) {
            const int hb = j*32 + hq*4;
            float4 k0 = *(const float4*)(kp + 0*HH + hb);
            float4 k1 = *(const float4*)(kp + 1*HH + hb);
            float4 k2 = *(const float4*)(kp + 2*HH + hb);
            float4 k3 = *(const float4*)(kp + 3*HH + hb);
            #pragma unroll
            for (int tt = 0; tt < 4; ++tt) {
                float4 qv = qr[tt][j];
                a0[tt] += fabsf(k0.x-qv.x)+fabsf(k0.y-qv.y)+fabsf(k0.z-qv.z)+fabsf(k0.w-qv.w);
                a1[tt] += fabsf(k1.x-qv.x)+fabsf(k1.y-qv.y)+fabsf(k1.z-qv.z)+fabsf(k1.w-qv.w);
                a2[tt] += fabsf(k2.x-qv.x)+fabsf(k2.y-qv.y)+fabsf(k2.z-qv.z)+fabsf(k2.w-qv.w);
                a3[tt] += fabsf(k3.x-qv.x)+fabsf(k3.y-qv.y)+fabsf(k3.z-qv.z)+fabsf(k3.w-qv.w);
            }
        }
        #pragma unroll
        for (int tt = 0; tt < 4; ++tt) {
            float v0=a0[tt], v1=a1[tt], v2=a2[tt], v3=a3[tt];
            v0 += __shfl_xor(v0,1); v0 += __shfl_xor(v0,2); v0 += __shfl_xor(v0,4);
            v1 += __shfl_xor(v1,1); v1 += __shfl_xor(v1,2); v1 += __shfl_xor(v1,4);
            v2 += __shfl_xor(v2,1); v2 += __shfl_xor(v2,2); v2 += __shfl_xor(v2,4);
            v3 += __shfl_xor(v3,1); v3 += __shfl_xor(v3,2); v3 += __shfl_xor(v3,4);
            if (hq == 0)
                *(float4*)&sbuf[wave][tt][pp*32 + cl*4] =
                    make_float4(-0.5f*v0, -0.5f*v1, -0.5f*v2, -0.5f*v3);
        }
    }
    // same-wave LDS handoff: no barrier

    // ---- single-pass softmax (wave-private; 16-lane group tg owns t-local tg) ----
    {
        const int tg = lane >> 4, ci = lane & 15;
        float4 x0 = *(const float4*)&sbuf[wave][tg][ci*8];
        float4 x1 = *(const float4*)&sbuf[wave][tg][ci*8 + 4];
        float m = fmaxf(fmaxf(fmaxf(x0.x,x0.y), fmaxf(x0.z,x0.w)),
                        fmaxf(fmaxf(x1.x,x1.y), fmaxf(x1.z,x1.w)));
        m = fmaxf(m, __shfl_xor(m,1)); m = fmaxf(m, __shfl_xor(m,2));
        m = fmaxf(m, __shfl_xor(m,4)); m = fmaxf(m, __shfl_xor(m,8));
        float e0 = __expf(x0.x-m), e1 = __expf(x0.y-m), e2 = __expf(x0.z-m), e3 = __expf(x0.w-m);
        float e4 = __expf(x1.x-m), e5 = __expf(x1.y-m), e6 = __expf(x1.z-m), e7 = __expf(x1.w-m);
        float sm = ((e0+e1)+(e2+e3)) + ((e4+e5)+(e6+e7));
        sm += __shfl_xor(sm,1); sm += __shfl_xor(sm,2);
        sm += __shfl_xor(sm,4); sm += __shfl_xor(sm,8);
        pTbuf[wave][ci*8+0][tg] = e0;  pTbuf[wave][ci*8+1][tg] = e1;
        pTbuf[wave][ci*8+2][tg] = e2;  pTbuf[wave][ci*8+3][tg] = e3;
        pTbuf[wave][ci*8+4][tg] = e4;  pTbuf[wave][ci*8+5][tg] = e5;
        pTbuf[wave][ci*8+6][tg] = e6;  pTbuf[wave][ci*8+7][tg] = e7;
        if (ci == 0) ml[wave][tg] = make_float2(m, sm);
    }
    // same-wave LDS handoff: no barrier

    // ---- PV over own 128 rows (reg acc, no rescale) ----
    const int cs = lane >> 5, hv = lane & 31;
    {
        float4 acc[4];
        #pragma unroll
        for (int tt = 0; tt < 4; ++tt) acc[tt] = make_float4(0.f,0.f,0.f,0.f);
        const float* vp = &value[(b*CC + cr*CPW + cs*64)*HH + hv*4];
        #pragma unroll 4
        for (int i = 0; i < 64; ++i) {
            float4 p4 = *(const float4*)&pTbuf[wave][cs*64 + i][0];  // broadcast
            float4 vv = *(const float4*)(vp + i*HH);                 // coalesced
            acc[0].x=fmaf(p4.x,vv.x,acc[0].x); acc[0].y=fmaf(p4.x,vv.y,acc[0].y);
            acc[0].z=fmaf(p4.x,vv.z,acc[0].z); acc[0].w=fmaf(p4.x,vv.w,acc[0].w);
            acc[1].x=fmaf(p4.y,vv.x,acc[1].x); acc[1].y=fmaf(p4.y,vv.y,acc[1].y);
            acc[1].z=fmaf(p4.y,vv.z,acc[1].z); acc[1].w=fmaf(p4.y,vv.w,acc[1].w);
            acc[2].x=fmaf(p4.z,vv.x,acc[2].x); acc[2].y=fmaf(p4.z,vv.y,acc[2].y);
            acc[2].z=fmaf(p4.z,vv.z,acc[2].z); acc[2].w=fmaf(p4.z,vv.w,acc[2].w);
            acc[3].x=fmaf(p4.w,vv.x,acc[3].x); acc[3].y=fmaf(p4.w,vv.y,acc[3].y);
            acc[3].z=fmaf(p4.w,vv.z,acc[3].z); acc[3].w=fmaf(p4.w,vv.w,acc[3].w);
        }
        // merge the two c-halves; lanes cs==0 publish
        #pragma unroll
        for (int tt = 0; tt < 4; ++tt) {
            acc[tt].x += __shfl_xor(acc[tt].x, 32);
            acc[tt].y += __shfl_xor(acc[tt].y, 32);
            acc[tt].z += __shfl_xor(acc[tt].z, 32);
            acc[tt].w += __shfl_xor(acc[tt].w, 32);
        }
        if (cs == 0) {
            #pragma unroll
            for (int tt = 0; tt < 4; ++tt)
                *(float4*)&partial[wave][tt][hv*4] = acc[tt];  // aliases own pT region: safe
        }
    }
    __syncthreads();

    // ---- flash-merge 4 c-ranges -> rep (aliases dead sbuf) ----
    #pragma unroll
    for (int e = tid; e < TT*HH; e += 512) {
        const int t = e >> 7, h = e & 127;
        const int thh = t >> 2, tt = t & 3;
        float2 q0 = ml[thh*4+0][tt], q1 = ml[thh*4+1][tt];
        float2 q2 = ml[thh*4+2][tt], q3 = ml[thh*4+3][tt];
        float M = fmaxf(fmaxf(q0.x,q1.x), fmaxf(q2.x,q3.x));
        float a0 = __expf(q0.x-M), a1 = __expf(q1.x-M);
        float a2 = __expf(q2.x-M), a3 = __expf(q3.x-M);
        float L = fmaf(a0,q0.y, fmaf(a1,q1.y, fmaf(a2,q2.y, a3*q3.y)));
        float r = a0*partial[thh*4+0][tt][h] + a1*partial[thh*4+1][tt][h]
                + a2*partial[thh*4+2][tt][h] + a3*partial[thh*4+3][tt][h];
        rep[t][h] = r / L;
    }
    __syncthreads();

    // ---- projection: thread (lt 0..3, h) -> rows lt and lt+4 ----
    {
        const int lt = tid >> 7, h = tid & 127;
        float o0 = b_tgt[h], o1 = o0;
        for (int k = 0; k < HH; k += 4) {
            float4 r0 = *(const float4*)&rep[lt    ][k];
            float4 r1 = *(const float4*)&rep[lt + 4][k];
            float w0 = W_tgt[(k+0)*HH + h];
            float w1 = W_tgt[(k+1)*HH + h];
            float w2 = W_tgt[(k+2)*HH + h];
            float w3 = W_tgt[(k+3)*HH + h];
            o0 = fmaf(r0.x,w0, fmaf(r0.y,w1, fmaf(r0.z,w2, fmaf(r0.w,w3, o0))));
            o1 = fmaf(r1.x,w0, fmaf(r1.y,w1, fmaf(r1.z,w2, fmaf(r1.w,w3, o1))));
        }
        out[(b*TDIM + t0 + lt    )*HH + h] = o0;
        out[(b*TDIM + t0 + lt + 4)*HH + h] = o1;
    }
}

extern "C" void kernel_launch(void* const* d_in, const int* in_sizes, int n_in,
                              void* d_out, int out_size, void* d_ws, size_t ws_size,
                              hipStream_t stream) {
    const float* ctx_x = (const float*)d_in[0];
    const float* ctx_y = (const float*)d_in[1];
    const float* tgt_x = (const float*)d_in[2];
    const float* W_in  = (const float*)d_in[3];
    const float* b_in  = (const float*)d_in[4];
    const float* W_ctx = (const float*)d_in[5];
    const float* b_ctx = (const float*)d_in[6];
    const float* W_tgt = (const float*)d_in[7];
    const float* b_tgt = (const float*)d_in[8];

    float* ws    = (float*)d_ws;
    float* key   = ws;                      // 262144 f32
    float* query = ws + 1*BB*CC*HH;         // 262144
    float* value = ws + 2*BB*CC*HH;         // 262144

    prep_kernel<<<BB*CC, 128, 0, stream>>>(ctx_x, ctx_y, tgt_x,
                                           W_in, b_in, W_ctx, b_ctx,
                                           key, query, value);
    fused_kernel<<<BB*(TDIM/TT), 512, 0, stream>>>(key, query, value,
                                                   W_tgt, b_tgt, (float*)d_out);
}